// Round 6
// baseline (421.619 us; speedup 1.0000x reference)
//
#include <hip/hip_runtime.h>

// Bottom-up HTMM on a complete 4-ary tree, depth 7 (t_size=21845).
// children(u)=4u+1..4u+4, pos(u)=(u-1)&3; only labels t[u*7] are data.
// prior cancels everywhere (only numbeta = prior*beta_il is used).
//
// TWO kernels total:
//   setup  : softmaxes -> transposed tables, zero out + sync words.
//   mega   : 256 blocks = 256 depth-3 subtrees (85 nodes, LDS state).
//            up(LDS) -> publish root beta (agent-scope stores) -> counter;
//            LAST block runs the 85-node top (global, validated bodies),
//            publishes subtree-root eps + flag; all blocks spin on the flag
//            (bounded), then run down(LDS, state still resident) + reduction.
// Cross-XCD rules honored: every cross-block datum is written AND read with
// agent-scope atomics (write-through); plain traffic stays block-local.
// grid.sync() measured ~25us/sync on 8-XCD MI355X (round 4) — avoided.

#define G 16
#define C 8
#define GC 128
#define TSIZE 21845
#define SL 5461

__device__ __forceinline__ float grp8_sum(float v) {
  v += __shfl_xor(v, 1);
  v += __shfl_xor(v, 2);
  v += __shfl_xor(v, 4);
  return v;
}

__device__ __forceinline__ void st_agent(float* p, float v) {
  __hip_atomic_store((unsigned int*)p, __float_as_uint(v),
                     __ATOMIC_RELAXED, __HIP_MEMORY_SCOPE_AGENT);
}
__device__ __forceinline__ float ld_agent(const float* p) {
  return __uint_as_float(__hip_atomic_load((const unsigned int*)p,
                         __ATOMIC_RELAXED, __HIP_MEMORY_SCOPE_AGENT));
}

// ---------------- setup: softmaxes + logs (transposed tables) -------------
__global__ void setup_kernel(const float* __restrict__ ain, const float* __restrict__ bin,
                             const float* __restrict__ piin, const float* __restrict__ spin,
                             float* __restrict__ a_sp, float* __restrict__ log_a,
                             float* __restrict__ sm_bT, float* __restrict__ log_bT,
                             float* __restrict__ sm_piT, float* __restrict__ log_piT,
                             float* __restrict__ log_sp, unsigned int* __restrict__ sync_,
                             float* __restrict__ out) {
  int blk = blockIdx.x, tid = threadIdx.x;
  if (blk < 16) {
    // softmax over labels (M=256) for b[g][c][:]; write transposed [lab][g*8+c]
    int g = blk;
    __shared__ float red4[4];
    for (int c = 0; c < 8; ++c) {
      int row = g * 8 + c;
      float x = bin[row * 256 + tid];
      float m = x;
      #pragma unroll
      for (int off2 = 32; off2; off2 >>= 1) m = fmaxf(m, __shfl_xor(m, off2));
      if ((tid & 63) == 0) red4[tid >> 6] = m;
      __syncthreads();
      m = fmaxf(fmaxf(red4[0], red4[1]), fmaxf(red4[2], red4[3]));
      __syncthreads();
      float e = expf(x - m);
      float ssum = e;
      #pragma unroll
      for (int off2 = 32; off2; off2 >>= 1) ssum += __shfl_xor(ssum, off2);
      if ((tid & 63) == 0) red4[tid >> 6] = ssum;
      __syncthreads();
      ssum = red4[0] + red4[1] + red4[2] + red4[3];
      __syncthreads();
      sm_bT[tid * GC + row]  = e / ssum;
      log_bT[tid * GC + row] = (x - m) - logf(ssum);
    }
  } else if (blk == 16) {
    // softmax of a over i (axis=1), times sm_sp -> a_sp; also log(sm_a)
    for (int col = tid; col < 512; col += 256) {
      int g = col >> 5, j = (col >> 2) & 7, l = col & 3;
      float x[8], m = -1e30f;
      #pragma unroll
      for (int i = 0; i < 8; ++i) { x[i] = ain[g*256 + i*32 + j*4 + l]; m = fmaxf(m, x[i]); }
      float ssum = 0.f;
      #pragma unroll
      for (int i = 0; i < 8; ++i) ssum += expf(x[i] - m);
      float ls = logf(ssum);
      float y0 = spin[g*4+0], y1 = spin[g*4+1], y2 = spin[g*4+2], y3 = spin[g*4+3];
      float ms = fmaxf(fmaxf(y0, y1), fmaxf(y2, y3));
      float d = expf(y0-ms) + expf(y1-ms) + expf(y2-ms) + expf(y3-ms);
      float spv = expf(spin[g*4+l] - ms) / d;
      #pragma unroll
      for (int i = 0; i < 8; ++i) {
        int o2 = g*256 + i*32 + j*4 + l;
        float smv = expf(x[i] - m) / ssum;
        a_sp[o2]  = smv * spv;
        log_a[o2] = (x[i] - m) - ls;
      }
    }
  } else {
    if (tid < 64) {
      // softmax of pi over c (axis=1) for each (g,l); transposed [l][g*8+c]
      int g = tid >> 2, l = tid & 3;
      float x[8], m = -1e30f;
      #pragma unroll
      for (int c = 0; c < 8; ++c) { x[c] = piin[g*32 + c*4 + l]; m = fmaxf(m, x[c]); }
      float ssum = 0.f;
      #pragma unroll
      for (int c = 0; c < 8; ++c) ssum += expf(x[c] - m);
      float ls = logf(ssum);
      #pragma unroll
      for (int c = 0; c < 8; ++c) {
        sm_piT[l*GC + g*8 + c]  = expf(x[c] - m) / ssum;
        log_piT[l*GC + g*8 + c] = (x[c] - m) - ls;
      }
    } else if (tid < 80) {
      // log softmax of sp over l
      int g = tid - 64;
      float y[4], m = -1e30f;
      #pragma unroll
      for (int l = 0; l < 4; ++l) { y[l] = spin[g*4 + l]; m = fmaxf(m, y[l]); }
      float ssum = 0.f;
      #pragma unroll
      for (int l = 0; l < 4; ++l) ssum += expf(y[l] - m);
      float ls = logf(ssum);
      #pragma unroll
      for (int l = 0; l < 4; ++l) log_sp[g*4 + l] = (y[l] - m) - ls;
    } else if (tid < 96) {
      out[tid - 80] = 0.0f;        // zero the accumulator (poisoned 0xAA)
    } else if (tid < 224) {
      sync_[tid - 96] = 0u;        // zero counter (+flag) words
    }
  }
}

// ---------------- LDS subtree bodies (validated rounds 4/5) ---------------
__device__ __forceinline__ void up_lds(int v, int lab, int gi, int g8,
    const float* asp, const float* __restrict__ sm_bT,
    float* sBeta, float* sNum) {
  int ch0 = 4*v + 1;
  float ub = 0.f;
  #pragma unroll
  for (int l = 0; l < 4; ++l) {
    const float4* bp = (const float4*)(sBeta + (ch0 + l)*GC + g8);
    float4 b0 = bp[0], b1 = bp[1];
    ub += asp[l]*b0.x + asp[4+l]*b0.y + asp[8+l]*b0.z + asp[12+l]*b0.w
        + asp[16+l]*b1.x + asp[20+l]*b1.y + asp[24+l]*b1.z + asp[28+l]*b1.w;
  }
  float tmp = sm_bT[lab*GC + gi] * ub;
  float s = grp8_sum(tmp);
  sBeta[v*GC + gi] = tmp / s;
  sNum[v*GC + gi]  = ub;
}

__device__ __forceinline__ double down_lds(int v, int lab, float e, int gi, int g8,
    const float* asp, const float* aal, const float* lsp,
    const float* __restrict__ log_bT, float* sBeta, const float* sNum) {
  float pe = e / sNum[v*GC + gi];
  int ch0 = 4*v + 1;
  float local = 0.f;
  #pragma unroll
  for (int l = 0; l < 4; ++l) {
    float4* bp = (float4*)(sBeta + (ch0 + l)*GC + g8);
    float4 b0 = bp[0], b1 = bp[1];
    float S = asp[l]*b0.x + asp[4+l]*b0.y + asp[8+l]*b0.z + asp[12+l]*b0.w
            + asp[16+l]*b1.x + asp[20+l]*b1.y + asp[24+l]*b1.z + asp[28+l]*b1.w;
    float A = aal[l]*b0.x + aal[4+l]*b0.y + aal[8+l]*b0.z + aal[12+l]*b0.w
            + aal[16+l]*b1.x + aal[20+l]*b1.y + aal[24+l]*b1.z + aal[28+l]*b1.w;
    float ce = pe * S;
    sBeta[(ch0 + l)*GC + gi] = ce;          // beta slot -> eps
    local += pe*A + ce*lsp[l];
  }
  return (double)local + (double)(e * log_bT[lab*GC + gi]);
}

// ---------------- global top bodies (last block only) ---------------------
__device__ __forceinline__ void up_gx(int u, int lab, int gi, int g8,
    const float* asp, const float* __restrict__ sm_bT,
    const float* __restrict__ childBeta,
    float* __restrict__ betaG, float* __restrict__ numG) {
  int ch0 = 4*u + 1;
  float ub = 0.f;
  #pragma unroll
  for (int l = 0; l < 4; ++l) {
    const float4* bp = (const float4*)(childBeta + (size_t)(ch0 + l)*GC + g8);
    float4 b0 = bp[0], b1 = bp[1];
    ub += asp[l]*b0.x + asp[4+l]*b0.y + asp[8+l]*b0.z + asp[12+l]*b0.w
        + asp[16+l]*b1.x + asp[20+l]*b1.y + asp[24+l]*b1.z + asp[28+l]*b1.w;
  }
  float tmp = sm_bT[lab*GC + gi] * ub;
  float s = grp8_sum(tmp);
  betaG[(size_t)u*GC + gi] = tmp / s;
  numG[(size_t)u*GC + gi]  = ub;
}

__device__ __forceinline__ double down_gx(int u, int lab, int gi, int g8,
    const float* asp, const float* aal, const float* lsp,
    const float* __restrict__ log_bT, const float* __restrict__ numG,
    const float* __restrict__ childBeta, float* __restrict__ epsG,
    bool publish) {
  float e  = epsG[(size_t)u*GC + gi];
  float pe = e / numG[(size_t)u*GC + gi];
  int ch0 = 4*u + 1;
  float local = 0.f;
  #pragma unroll
  for (int l = 0; l < 4; ++l) {
    const float4* bp = (const float4*)(childBeta + (size_t)(ch0 + l)*GC + g8);
    float4 b0 = bp[0], b1 = bp[1];
    float S = asp[l]*b0.x + asp[4+l]*b0.y + asp[8+l]*b0.z + asp[12+l]*b0.w
            + asp[16+l]*b1.x + asp[20+l]*b1.y + asp[24+l]*b1.z + asp[28+l]*b1.w;
    float A = aal[l]*b0.x + aal[4+l]*b0.y + aal[8+l]*b0.z + aal[12+l]*b0.w
            + aal[16+l]*b1.x + aal[20+l]*b1.y + aal[24+l]*b1.z + aal[28+l]*b1.w;
    float ce = pe * S;
    if (publish) st_agent(&epsG[(size_t)(ch0 + l)*GC + gi], ce);
    else         epsG[(size_t)(ch0 + l)*GC + gi] = ce;
    local += pe*A + ce*lsp[l];
  }
  return (double)local + (double)(e * log_bT[lab*GC + gi]);
}

// ---------------- mega: up + (last-block top) + down ----------------------
__global__ __launch_bounds__(1024, 1) void mega_kernel(
    const float* __restrict__ a_sp, const float* __restrict__ log_a,
    const float* __restrict__ log_sp, const float* __restrict__ sm_bT,
    const float* __restrict__ log_bT, const float* __restrict__ sm_piT,
    const float* __restrict__ log_piT, const int* __restrict__ t,
    float* __restrict__ betaG, float* __restrict__ numG,
    float* __restrict__ epsG, unsigned int* __restrict__ sync_,
    float* __restrict__ out) {
  __shared__ float  sBeta[85*GC];           // 42.5 KB; down overwrites w/ eps
  __shared__ float  sNum[21*GC];            // 10.5 KB
  __shared__ double sd[128];
  __shared__ int    sLast;
  const int blk = blockIdx.x, tid = threadIdx.x;
  const int gi = tid & 127, g = gi >> 3, i = gi & 7, g8 = g*8, w = tid >> 7;
  float asp[32], aal[32], lsp[4];
  {
    const float4* pa = (const float4*)(a_sp  + g*256 + i*32);
    const float4* pl = (const float4*)(log_a + g*256 + i*32);
    #pragma unroll
    for (int k = 0; k < 8; ++k) {
      float4 va = pa[k], vl = pl[k];
      asp[k*4+0]=va.x; asp[k*4+1]=va.y; asp[k*4+2]=va.z; asp[k*4+3]=va.w;
      aal[k*4+0]=va.x*vl.x; aal[k*4+1]=va.y*vl.y; aal[k*4+2]=va.z*vl.z; aal[k*4+3]=va.w*vl.w;
    }
    #pragma unroll
    for (int l = 0; l < 4; ++l) lsp[l] = log_sp[g*4 + l];
  }
  const int base_leaf = SL + blk*64;

  // ======== subtree up (LDS), keep sNum for the later down phase ========
  #pragma unroll
  for (int it = 0; it < 8; ++it) {          // leaves: locals 21..84
    int k = it*8 + w;
    float bt = sm_piT[(k & 3)*GC + gi] * sm_bT[t[(base_leaf + k)*7]*GC + gi];
    float s = grp8_sum(bt);
    sBeta[(21 + k)*GC + gi] = bt / s;
  }
  __syncthreads();
  #pragma unroll
  for (int it = 0; it < 2; ++it) {          // level 6: locals 5..20
    int k = it*8 + w;
    up_lds(5 + k, t[(1365 + blk*16 + k)*7], gi, g8, asp, sm_bT, sBeta, sNum);
  }
  __syncthreads();
  if (tid < 512)                            // level 5: locals 1..4
    up_lds(1 + w, t[(341 + blk*4 + w)*7], gi, g8, asp, sm_bT, sBeta, sNum);
  __syncthreads();
  if (tid < 128) {                          // subtree root: local 0
    up_lds(0, t[(85 + blk)*7], gi, g8, asp, sm_bT, sBeta, sNum);
    st_agent(&betaG[(size_t)(85 + blk)*GC + gi], sBeta[gi]);  // publish
  }
  __syncthreads();                          // all publishes issued & drained
  if (tid == 0) {
    __threadfence();
    unsigned int prev = __hip_atomic_fetch_add(&sync_[0], 1u,
                          __ATOMIC_ACQ_REL, __HIP_MEMORY_SCOPE_AGENT);
    sLast = (prev == 255u);
  }
  __syncthreads();

  // ======== top: executed by the LAST-arriving block only ========
  if (sLast) {
    const int q = tid >> 7;                 // 0..7
    // gather all 256 published roots into epsG scratch (agent loads)
    #pragma unroll
    for (int it = 0; it < 32; ++it) {
      int idx = it*1024 + tid;              // 0..32767
      float v = ld_agent(&betaG[(size_t)85*GC + idx]);
      st_agent(&epsG[(size_t)85*GC + idx], v);   // write-through scratch
    }
    __syncthreads();
    #pragma unroll
    for (int it = 0; it < 8; ++it)          // up level 3 (children = roots)
      up_gx(21 + it*8 + q, t[(21 + it*8 + q)*7], gi, g8, asp, sm_bT,
            epsG, betaG, numG);
    __syncthreads();
    #pragma unroll
    for (int it = 0; it < 2; ++it)          // up level 2
      up_gx(5 + it*8 + q, t[(5 + it*8 + q)*7], gi, g8, asp, sm_bT,
            betaG, betaG, numG);
    __syncthreads();
    if (tid < 512)                          // up level 1
      up_gx(1 + q, t[(1 + q)*7], gi, g8, asp, sm_bT, betaG, betaG, numG);
    __syncthreads();
    if (tid < 128) {                        // root
      up_gx(0, t[0], gi, g8, asp, sm_bT, betaG, betaG, numG);
      epsG[gi] = betaG[gi];                 // eps root = beta root
    }
    __syncthreads();
    double acc = 0.0;
    if (tid < 128)
      acc += down_gx(0, t[0], gi, g8, asp, aal, lsp, log_bT, numG,
                     betaG, epsG, false);
    __syncthreads();
    if (tid < 512)
      acc += down_gx(1 + q, t[(1 + q)*7], gi, g8, asp, aal, lsp, log_bT, numG,
                     betaG, epsG, false);
    __syncthreads();
    #pragma unroll
    for (int it = 0; it < 2; ++it)
      acc += down_gx(5 + it*8 + q, t[(5 + it*8 + q)*7], gi, g8, asp, aal, lsp,
                     log_bT, numG, betaG, epsG, false);
    __syncthreads();
    #pragma unroll
    for (int it = 0; it < 8; ++it)          // level 3: in-place on scratch,
      acc += down_gx(21 + it*8 + q, t[(21 + it*8 + q)*7], gi, g8, asp, aal,
                     lsp, log_bT, numG, epsG, epsG, true);  // publish eps
    // top contribution -> out
    acc += __shfl_xor(acc, 1);
    acc += __shfl_xor(acc, 2);
    acc += __shfl_xor(acc, 4);
    if (i == 0) sd[tid >> 3] = acc;
    __syncthreads();
    if (tid < 16) {
      double s = 0.0;
      #pragma unroll
      for (int c2 = 0; c2 < 8; ++c2) s += sd[tid + 16*c2];
      atomicAdd(&out[tid], (float)s);
    }
    __syncthreads();
    if (tid == 0) {
      __threadfence();
      __hip_atomic_store(&sync_[64], 1u, __ATOMIC_RELEASE,
                         __HIP_MEMORY_SCOPE_AGENT);
    }
  }

  // ======== wait for top's eps publish (bounded spin) ========
  if (tid == 0) {
    long itc = 0;
    while (__hip_atomic_load(&sync_[64], __ATOMIC_ACQUIRE,
                             __HIP_MEMORY_SCOPE_AGENT) == 0u &&
           itc < (1L << 21)) {
      ++itc;
      __builtin_amdgcn_s_sleep(2);
    }
  }
  __syncthreads();

  // ======== subtree down (LDS state still resident) + reduction ========
  double acc = 0.0;
  if (tid < 128) {
    float e = ld_agent(&epsG[(size_t)(85 + blk)*GC + gi]);
    acc += down_lds(0, t[(85 + blk)*7], e, gi, g8, asp, aal, lsp, log_bT,
                    sBeta, sNum);
  }
  __syncthreads();
  if (tid < 512) {                          // level 5 (locals 1..4)
    int v = 1 + w;
    float e = sBeta[v*GC + gi];
    acc += down_lds(v, t[(341 + blk*4 + w)*7], e, gi, g8, asp, aal, lsp,
                    log_bT, sBeta, sNum);
  }
  __syncthreads();
  #pragma unroll
  for (int it = 0; it < 2; ++it) {          // level 6 (locals 5..20)
    int k = it*8 + w, v = 5 + k;
    float e = sBeta[v*GC + gi];
    acc += down_lds(v, t[(1365 + blk*16 + k)*7], e, gi, g8, asp, aal, lsp,
                    log_bT, sBeta, sNum);
  }
  __syncthreads();
  #pragma unroll
  for (int it = 0; it < 8; ++it) {          // leaves: b_lh + pi_lh
    int k = it*8 + w;
    float e = sBeta[(21 + k)*GC + gi];
    acc += (double)(e * (log_bT[t[(base_leaf + k)*7]*GC + gi] +
                         log_piT[(k & 3)*GC + gi]));
  }
  acc += __shfl_xor(acc, 1);
  acc += __shfl_xor(acc, 2);
  acc += __shfl_xor(acc, 4);
  if (i == 0) sd[tid >> 3] = acc;           // tid>>3 = chunk*16 + g
  __syncthreads();
  if (tid < 16) {
    double s = 0.0;
    #pragma unroll
    for (int c2 = 0; c2 < 8; ++c2) s += sd[tid + 16*c2];
    atomicAdd(&out[tid], (float)s);
  }
}

extern "C" void kernel_launch(void* const* d_in, const int* in_sizes, int n_in,
                              void* d_out, int out_size, void* d_ws, size_t ws_size,
                              hipStream_t stream) {
  const int*   t  = (const int*)d_in[0];
  // d_in[1] = t_limits (tree shape is compile-time constant)
  const float* a  = (const float*)d_in[2];
  const float* b  = (const float*)d_in[3];
  const float* pi = (const float*)d_in[4];
  const float* sp = (const float*)d_in[5];
  float* out = (float*)d_out;

  char* w = (char*)d_ws;
  size_t off = 0;
  auto carve = [&](size_t bytes) -> void* {
    void* ptr = w + off;
    off += (bytes + 255) & ~(size_t)255;
    return ptr;
  };
  float* a_sp    = (float*)carve((size_t)16*8*8*4*4);
  float* log_a   = (float*)carve((size_t)16*8*8*4*4);
  float* sm_bT   = (float*)carve((size_t)256*GC*4);
  float* log_bT  = (float*)carve((size_t)256*GC*4);
  float* sm_piT  = (float*)carve((size_t)4*GC*4);
  float* log_piT = (float*)carve((size_t)4*GC*4);
  float* log_sp  = (float*)carve((size_t)16*4*4);
  float* betaG   = (float*)carve((size_t)341*GC*4);   // top + subtree roots
  float* numG    = (float*)carve((size_t)85*GC*4);    // top internal
  float* epsG    = (float*)carve((size_t)341*GC*4);   // top eps + root scratch
  unsigned int* sync_ = (unsigned int*)carve(512);    // [0]=counter, [64]=flag

  setup_kernel<<<18, 256, 0, stream>>>(a, b, pi, sp, a_sp, log_a, sm_bT, log_bT,
                                       sm_piT, log_piT, log_sp, sync_, out);
  mega_kernel<<<256, 1024, 0, stream>>>(a_sp, log_a, log_sp, sm_bT, log_bT,
                                        sm_piT, log_piT, t, betaG, numG, epsG,
                                        sync_, out);
}

// Round 7
// 175.180 us; speedup vs baseline: 2.4068x; 2.4068x over previous
//
#include <hip/hip_runtime.h>

// Bottom-up HTMM on a complete 4-ary tree, depth 7 (t_size=21845).
// children(u)=4u+1..4u+4, pos(u)=(u-1)&3; only labels t[u*7] are data.
// prior cancels everywhere (only numbeta = prior*beta_il is used).
//
// THREE kernels (no intra-kernel cross-block waiting — R6 showed spin-wait
// costs ~350us on 8-XCD MI355X; R4 showed grid.sync costs ~25us each):
//   setup : softmaxes -> transposed tables, zero out + sync counter.
//   uptop : 256 blocks = 256 depth-3 subtrees (LDS state). Each publishes its
//           root beta (agent-scope write-through stores), bumps a counter and
//           EXITS. The unique last-arriving block (prev==255) runs the 85-node
//           top (global, plain loads of published roots — fresh from L3 since
//           never locally cached; pattern validated in R6) and writes the
//           subtree-root eps with plain stores (kernel boundary flushes).
//   down  : 256 blocks redo subtree up in LDS, then down + fused reduction.

#define G 16
#define C 8
#define GC 128
#define TSIZE 21845
#define SL 5461

__device__ __forceinline__ float grp8_sum(float v) {
  v += __shfl_xor(v, 1);
  v += __shfl_xor(v, 2);
  v += __shfl_xor(v, 4);
  return v;
}

__device__ __forceinline__ void st_agent(float* p, float v) {
  __hip_atomic_store((unsigned int*)p, __float_as_uint(v),
                     __ATOMIC_RELAXED, __HIP_MEMORY_SCOPE_AGENT);
}

// ---------------- setup: softmaxes + logs (transposed tables) -------------
__global__ void setup_kernel(const float* __restrict__ ain, const float* __restrict__ bin,
                             const float* __restrict__ piin, const float* __restrict__ spin,
                             float* __restrict__ a_sp, float* __restrict__ log_a,
                             float* __restrict__ sm_bT, float* __restrict__ log_bT,
                             float* __restrict__ sm_piT, float* __restrict__ log_piT,
                             float* __restrict__ log_sp, unsigned int* __restrict__ sync_,
                             float* __restrict__ out) {
  int blk = blockIdx.x, tid = threadIdx.x;
  if (blk < 16) {
    // softmax over labels (M=256) for b[g][c][:]; write transposed [lab][g*8+c]
    int g = blk;
    __shared__ float red4[4];
    for (int c = 0; c < 8; ++c) {
      int row = g * 8 + c;
      float x = bin[row * 256 + tid];
      float m = x;
      #pragma unroll
      for (int off2 = 32; off2; off2 >>= 1) m = fmaxf(m, __shfl_xor(m, off2));
      if ((tid & 63) == 0) red4[tid >> 6] = m;
      __syncthreads();
      m = fmaxf(fmaxf(red4[0], red4[1]), fmaxf(red4[2], red4[3]));
      __syncthreads();
      float e = expf(x - m);
      float ssum = e;
      #pragma unroll
      for (int off2 = 32; off2; off2 >>= 1) ssum += __shfl_xor(ssum, off2);
      if ((tid & 63) == 0) red4[tid >> 6] = ssum;
      __syncthreads();
      ssum = red4[0] + red4[1] + red4[2] + red4[3];
      __syncthreads();
      sm_bT[tid * GC + row]  = e / ssum;
      log_bT[tid * GC + row] = (x - m) - logf(ssum);
    }
  } else if (blk == 16) {
    // softmax of a over i (axis=1), times sm_sp -> a_sp; also log(sm_a)
    for (int col = tid; col < 512; col += 256) {
      int g = col >> 5, j = (col >> 2) & 7, l = col & 3;
      float x[8], m = -1e30f;
      #pragma unroll
      for (int i = 0; i < 8; ++i) { x[i] = ain[g*256 + i*32 + j*4 + l]; m = fmaxf(m, x[i]); }
      float ssum = 0.f;
      #pragma unroll
      for (int i = 0; i < 8; ++i) ssum += expf(x[i] - m);
      float ls = logf(ssum);
      float y0 = spin[g*4+0], y1 = spin[g*4+1], y2 = spin[g*4+2], y3 = spin[g*4+3];
      float ms = fmaxf(fmaxf(y0, y1), fmaxf(y2, y3));
      float d = expf(y0-ms) + expf(y1-ms) + expf(y2-ms) + expf(y3-ms);
      float spv = expf(spin[g*4+l] - ms) / d;
      #pragma unroll
      for (int i = 0; i < 8; ++i) {
        int o2 = g*256 + i*32 + j*4 + l;
        float smv = expf(x[i] - m) / ssum;
        a_sp[o2]  = smv * spv;
        log_a[o2] = (x[i] - m) - ls;
      }
    }
  } else {
    if (tid < 64) {
      // softmax of pi over c (axis=1) for each (g,l); transposed [l][g*8+c]
      int g = tid >> 2, l = tid & 3;
      float x[8], m = -1e30f;
      #pragma unroll
      for (int c = 0; c < 8; ++c) { x[c] = piin[g*32 + c*4 + l]; m = fmaxf(m, x[c]); }
      float ssum = 0.f;
      #pragma unroll
      for (int c = 0; c < 8; ++c) ssum += expf(x[c] - m);
      float ls = logf(ssum);
      #pragma unroll
      for (int c = 0; c < 8; ++c) {
        sm_piT[l*GC + g*8 + c]  = expf(x[c] - m) / ssum;
        log_piT[l*GC + g*8 + c] = (x[c] - m) - ls;
      }
    } else if (tid < 80) {
      // log softmax of sp over l
      int g = tid - 64;
      float y[4], m = -1e30f;
      #pragma unroll
      for (int l = 0; l < 4; ++l) { y[l] = spin[g*4 + l]; m = fmaxf(m, y[l]); }
      float ssum = 0.f;
      #pragma unroll
      for (int l = 0; l < 4; ++l) ssum += expf(y[l] - m);
      float ls = logf(ssum);
      #pragma unroll
      for (int l = 0; l < 4; ++l) log_sp[g*4 + l] = (y[l] - m) - ls;
    } else if (tid < 96) {
      out[tid - 80] = 0.0f;        // zero the accumulator (poisoned 0xAA)
    } else if (tid < 224) {
      sync_[tid - 96] = 0u;        // zero counter words
    }
  }
}

// ---------------- LDS subtree bodies (validated rounds 4/5/6) -------------
__device__ __forceinline__ void up_lds(int v, int lab, int gi, int g8,
    const float* asp, const float* __restrict__ sm_bT,
    float* sBeta, float* sNum, bool wantNum) {
  int ch0 = 4*v + 1;
  float ub = 0.f;
  #pragma unroll
  for (int l = 0; l < 4; ++l) {
    const float4* bp = (const float4*)(sBeta + (ch0 + l)*GC + g8);
    float4 b0 = bp[0], b1 = bp[1];
    ub += asp[l]*b0.x + asp[4+l]*b0.y + asp[8+l]*b0.z + asp[12+l]*b0.w
        + asp[16+l]*b1.x + asp[20+l]*b1.y + asp[24+l]*b1.z + asp[28+l]*b1.w;
  }
  float tmp = sm_bT[lab*GC + gi] * ub;
  float s = grp8_sum(tmp);
  sBeta[v*GC + gi] = tmp / s;
  if (wantNum) sNum[v*GC + gi] = ub;
}

__device__ __forceinline__ double down_lds(int v, int lab, float e, int gi, int g8,
    const float* asp, const float* aal, const float* lsp,
    const float* __restrict__ log_bT, float* sBeta, const float* sNum) {
  float pe = e / sNum[v*GC + gi];
  int ch0 = 4*v + 1;
  float local = 0.f;
  #pragma unroll
  for (int l = 0; l < 4; ++l) {
    float4* bp = (float4*)(sBeta + (ch0 + l)*GC + g8);
    float4 b0 = bp[0], b1 = bp[1];
    float S = asp[l]*b0.x + asp[4+l]*b0.y + asp[8+l]*b0.z + asp[12+l]*b0.w
            + asp[16+l]*b1.x + asp[20+l]*b1.y + asp[24+l]*b1.z + asp[28+l]*b1.w;
    float A = aal[l]*b0.x + aal[4+l]*b0.y + aal[8+l]*b0.z + aal[12+l]*b0.w
            + aal[16+l]*b1.x + aal[20+l]*b1.y + aal[24+l]*b1.z + aal[28+l]*b1.w;
    float ce = pe * S;
    sBeta[(ch0 + l)*GC + gi] = ce;          // beta slot -> eps
    local += pe*A + ce*lsp[l];
  }
  return (double)local + (double)(e * log_bT[lab*GC + gi]);
}

// ---------------- global top bodies (last block only; plain mem ops) ------
__device__ __forceinline__ void up_g(int u, int lab, int gi, int g8,
    const float* asp, const float* __restrict__ sm_bT,
    float* __restrict__ betaG, float* __restrict__ numG) {
  int ch0 = 4*u + 1;
  float ub = 0.f;
  #pragma unroll
  for (int l = 0; l < 4; ++l) {
    const float4* bp = (const float4*)(betaG + (size_t)(ch0 + l)*GC + g8);
    float4 b0 = bp[0], b1 = bp[1];
    ub += asp[l]*b0.x + asp[4+l]*b0.y + asp[8+l]*b0.z + asp[12+l]*b0.w
        + asp[16+l]*b1.x + asp[20+l]*b1.y + asp[24+l]*b1.z + asp[28+l]*b1.w;
  }
  float tmp = sm_bT[lab*GC + gi] * ub;
  float s = grp8_sum(tmp);
  betaG[(size_t)u*GC + gi] = tmp / s;
  numG[(size_t)u*GC + gi]  = ub;
}

__device__ __forceinline__ double down_g(int u, int lab, int gi, int g8,
    const float* asp, const float* aal, const float* lsp,
    const float* __restrict__ log_bT, const float* __restrict__ numG,
    const float* __restrict__ betaG, float* __restrict__ epsG) {
  float e  = epsG[(size_t)u*GC + gi];
  float pe = e / numG[(size_t)u*GC + gi];
  int ch0 = 4*u + 1;
  float local = 0.f;
  #pragma unroll
  for (int l = 0; l < 4; ++l) {
    const float4* bp = (const float4*)(betaG + (size_t)(ch0 + l)*GC + g8);
    float4 b0 = bp[0], b1 = bp[1];
    float S = asp[l]*b0.x + asp[4+l]*b0.y + asp[8+l]*b0.z + asp[12+l]*b0.w
            + asp[16+l]*b1.x + asp[20+l]*b1.y + asp[24+l]*b1.z + asp[28+l]*b1.w;
    float A = aal[l]*b0.x + aal[4+l]*b0.y + aal[8+l]*b0.z + aal[12+l]*b0.w
            + aal[16+l]*b1.x + aal[20+l]*b1.y + aal[24+l]*b1.z + aal[28+l]*b1.w;
    float ce = pe * S;
    epsG[(size_t)(ch0 + l)*GC + gi] = ce;   // plain; kernel boundary flushes
    local += pe*A + ce*lsp[l];
  }
  return (double)local + (double)(e * log_bT[lab*GC + gi]);
}

// ---------------- uptop: subtree up; last block runs the top --------------
__global__ __launch_bounds__(1024, 1) void uptop_kernel(
    const float* __restrict__ a_sp, const float* __restrict__ log_a,
    const float* __restrict__ log_sp, const float* __restrict__ sm_bT,
    const float* __restrict__ log_bT, const float* __restrict__ sm_piT,
    const int* __restrict__ t, float* __restrict__ betaG,
    float* __restrict__ numG, float* __restrict__ epsG,
    unsigned int* __restrict__ sync_, float* __restrict__ out) {
  __shared__ float  sBeta[85*GC];           // 42.5 KB
  __shared__ double sd[128];
  __shared__ int    sLast;
  const int blk = blockIdx.x, tid = threadIdx.x;
  const int gi = tid & 127, g = gi >> 3, i = gi & 7, g8 = g*8, w = tid >> 7;
  float asp[32];
  {
    const float4* pa = (const float4*)(a_sp + g*256 + i*32);
    #pragma unroll
    for (int q = 0; q < 8; ++q) {
      float4 v = pa[q];
      asp[q*4+0]=v.x; asp[q*4+1]=v.y; asp[q*4+2]=v.z; asp[q*4+3]=v.w;
    }
  }
  const int base_leaf = SL + blk*64;
  // ---- subtree up (LDS), identical to R5 up_kernel ----
  #pragma unroll
  for (int it = 0; it < 8; ++it) {          // leaves: locals 21..84
    int k = it*8 + w;
    float bt = sm_piT[(k & 3)*GC + gi] * sm_bT[t[(base_leaf + k)*7]*GC + gi];
    float s = grp8_sum(bt);
    sBeta[(21 + k)*GC + gi] = bt / s;
  }
  __syncthreads();
  #pragma unroll
  for (int it = 0; it < 2; ++it) {          // level 6: locals 5..20
    int k = it*8 + w;
    up_lds(5 + k, t[(1365 + blk*16 + k)*7], gi, g8, asp, sm_bT, sBeta, nullptr, false);
  }
  __syncthreads();
  if (tid < 512)                            // level 5: locals 1..4
    up_lds(1 + w, t[(341 + blk*4 + w)*7], gi, g8, asp, sm_bT, sBeta, nullptr, false);
  __syncthreads();
  if (tid < 128) {                          // subtree root: local 0
    up_lds(0, t[(85 + blk)*7], gi, g8, asp, sm_bT, sBeta, nullptr, false);
    st_agent(&betaG[(size_t)(85 + blk)*GC + gi], sBeta[gi]);  // publish
  }
  __syncthreads();                          // publishes drained from CU
  if (tid == 0) {
    __threadfence();
    unsigned int prev = __hip_atomic_fetch_add(&sync_[0], 1u,
                          __ATOMIC_ACQ_REL, __HIP_MEMORY_SCOPE_AGENT);
    sLast = (prev == 255u);
  }
  __syncthreads();
  if (!sLast) return;                       // 255 blocks exit — NO waiting

  // ---- top: last block only (sees all 256 published roots) ----
  const int q = tid >> 7;
  float aal[32], lsp[4];
  {
    const float4* pa = (const float4*)(a_sp  + g*256 + i*32);
    const float4* pl = (const float4*)(log_a + g*256 + i*32);
    #pragma unroll
    for (int k = 0; k < 8; ++k) {
      float4 va = pa[k], vl = pl[k];
      aal[k*4+0]=va.x*vl.x; aal[k*4+1]=va.y*vl.y; aal[k*4+2]=va.z*vl.z; aal[k*4+3]=va.w*vl.w;
    }
    #pragma unroll
    for (int l = 0; l < 4; ++l) lsp[l] = log_sp[g*4 + l];
  }
  #pragma unroll
  for (int it = 0; it < 8; ++it)            // up level 3 (children = roots)
    up_g(21 + it*8 + q, t[(21 + it*8 + q)*7], gi, g8, asp, sm_bT, betaG, numG);
  __syncthreads();
  #pragma unroll
  for (int it = 0; it < 2; ++it)            // up level 2
    up_g(5 + it*8 + q, t[(5 + it*8 + q)*7], gi, g8, asp, sm_bT, betaG, numG);
  __syncthreads();
  if (tid < 512)                            // up level 1
    up_g(1 + q, t[(1 + q)*7], gi, g8, asp, sm_bT, betaG, numG);
  __syncthreads();
  if (tid < 128) {                          // root
    up_g(0, t[0], gi, g8, asp, sm_bT, betaG, numG);
    epsG[gi] = betaG[gi];                   // eps root = beta root
  }
  __syncthreads();
  double acc = 0.0;
  if (tid < 128)
    acc += down_g(0, t[0], gi, g8, asp, aal, lsp, log_bT, numG, betaG, epsG);
  __syncthreads();
  if (tid < 512)
    acc += down_g(1 + q, t[(1 + q)*7], gi, g8, asp, aal, lsp, log_bT, numG, betaG, epsG);
  __syncthreads();
  #pragma unroll
  for (int it = 0; it < 2; ++it)
    acc += down_g(5 + it*8 + q, t[(5 + it*8 + q)*7], gi, g8, asp, aal, lsp,
                  log_bT, numG, betaG, epsG);
  __syncthreads();
  #pragma unroll
  for (int it = 0; it < 8; ++it)            // level 3: writes eps for roots
    acc += down_g(21 + it*8 + q, t[(21 + it*8 + q)*7], gi, g8, asp, aal, lsp,
                  log_bT, numG, betaG, epsG);
  // top contribution -> out
  acc += __shfl_xor(acc, 1);
  acc += __shfl_xor(acc, 2);
  acc += __shfl_xor(acc, 4);
  if (i == 0) sd[tid >> 3] = acc;           // tid>>3 = w*16 + g
  __syncthreads();
  if (tid < 16) {
    double s = 0.0;
    #pragma unroll
    for (int c2 = 0; c2 < 8; ++c2) s += sd[tid + 16*c2];
    atomicAdd(&out[tid], (float)s);
  }
}

// ---------------- down: redo subtree up in LDS, then down + reduction -----
__global__ __launch_bounds__(1024, 1) void down_kernel(
    const float* __restrict__ a_sp, const float* __restrict__ log_a,
    const float* __restrict__ log_sp, const float* __restrict__ sm_bT,
    const float* __restrict__ log_bT, const float* __restrict__ sm_piT,
    const float* __restrict__ log_piT, const int* __restrict__ t,
    const float* __restrict__ epsG, float* __restrict__ out) {
  __shared__ float  sBeta[85*GC];           // 42.5 KB; down overwrites w/ eps
  __shared__ float  sNum[21*GC];            // 10.5 KB
  __shared__ double sd[128];
  const int blk = blockIdx.x, tid = threadIdx.x;
  const int gi = tid & 127, g = gi >> 3, i = gi & 7, g8 = g*8, w = tid >> 7;
  float asp[32], aal[32], lsp[4];
  {
    const float4* pa = (const float4*)(a_sp  + g*256 + i*32);
    const float4* pl = (const float4*)(log_a + g*256 + i*32);
    #pragma unroll
    for (int k = 0; k < 8; ++k) {
      float4 va = pa[k], vl = pl[k];
      asp[k*4+0]=va.x; asp[k*4+1]=va.y; asp[k*4+2]=va.z; asp[k*4+3]=va.w;
      aal[k*4+0]=va.x*vl.x; aal[k*4+1]=va.y*vl.y; aal[k*4+2]=va.z*vl.z; aal[k*4+3]=va.w*vl.w;
    }
    #pragma unroll
    for (int l = 0; l < 4; ++l) lsp[l] = log_sp[g*4 + l];
  }
  const int base_leaf = SL + blk*64;
  // ---- redo up (cheap; avoids a 14MB global round-trip) ----
  #pragma unroll
  for (int it = 0; it < 8; ++it) {
    int k = it*8 + w;
    float bt = sm_piT[(k & 3)*GC + gi] * sm_bT[t[(base_leaf + k)*7]*GC + gi];
    float s = grp8_sum(bt);
    sBeta[(21 + k)*GC + gi] = bt / s;
  }
  __syncthreads();
  #pragma unroll
  for (int it = 0; it < 2; ++it) {
    int k = it*8 + w;
    up_lds(5 + k, t[(1365 + blk*16 + k)*7], gi, g8, asp, sm_bT, sBeta, sNum, true);
  }
  __syncthreads();
  if (tid < 512)
    up_lds(1 + w, t[(341 + blk*4 + w)*7], gi, g8, asp, sm_bT, sBeta, sNum, true);
  __syncthreads();
  double acc = 0.0;
  if (tid < 128) {
    up_lds(0, t[(85 + blk)*7], gi, g8, asp, sm_bT, sBeta, sNum, true);
    float e = epsG[(size_t)(85 + blk)*GC + gi];   // from uptop's last block
    acc += down_lds(0, t[(85 + blk)*7], e, gi, g8, asp, aal, lsp, log_bT,
                    sBeta, sNum);
  }
  __syncthreads();
  if (tid < 512) {                          // down level 5 (locals 1..4)
    int v = 1 + w;
    float e = sBeta[v*GC + gi];
    acc += down_lds(v, t[(341 + blk*4 + w)*7], e, gi, g8, asp, aal, lsp,
                    log_bT, sBeta, sNum);
  }
  __syncthreads();
  #pragma unroll
  for (int it = 0; it < 2; ++it) {          // down level 6 (locals 5..20)
    int k = it*8 + w, v = 5 + k;
    float e = sBeta[v*GC + gi];
    acc += down_lds(v, t[(1365 + blk*16 + k)*7], e, gi, g8, asp, aal, lsp,
                    log_bT, sBeta, sNum);
  }
  __syncthreads();
  #pragma unroll
  for (int it = 0; it < 8; ++it) {          // leaves: b_lh + pi_lh
    int k = it*8 + w;
    float e = sBeta[(21 + k)*GC + gi];
    acc += (double)(e * (log_bT[t[(base_leaf + k)*7]*GC + gi] +
                         log_piT[(k & 3)*GC + gi]));
  }
  acc += __shfl_xor(acc, 1);
  acc += __shfl_xor(acc, 2);
  acc += __shfl_xor(acc, 4);
  if (i == 0) sd[tid >> 3] = acc;           // tid>>3 = w*16 + g
  __syncthreads();
  if (tid < 16) {
    double s = 0.0;
    #pragma unroll
    for (int c2 = 0; c2 < 8; ++c2) s += sd[tid + 16*c2];
    atomicAdd(&out[tid], (float)s);
  }
}

extern "C" void kernel_launch(void* const* d_in, const int* in_sizes, int n_in,
                              void* d_out, int out_size, void* d_ws, size_t ws_size,
                              hipStream_t stream) {
  const int*   t  = (const int*)d_in[0];
  // d_in[1] = t_limits (tree shape is compile-time constant)
  const float* a  = (const float*)d_in[2];
  const float* b  = (const float*)d_in[3];
  const float* pi = (const float*)d_in[4];
  const float* sp = (const float*)d_in[5];
  float* out = (float*)d_out;

  char* w = (char*)d_ws;
  size_t off = 0;
  auto carve = [&](size_t bytes) -> void* {
    void* ptr = w + off;
    off += (bytes + 255) & ~(size_t)255;
    return ptr;
  };
  float* a_sp    = (float*)carve((size_t)16*8*8*4*4);
  float* log_a   = (float*)carve((size_t)16*8*8*4*4);
  float* sm_bT   = (float*)carve((size_t)256*GC*4);
  float* log_bT  = (float*)carve((size_t)256*GC*4);
  float* sm_piT  = (float*)carve((size_t)4*GC*4);
  float* log_piT = (float*)carve((size_t)4*GC*4);
  float* log_sp  = (float*)carve((size_t)16*4*4);
  float* betaG   = (float*)carve((size_t)341*GC*4);   // top + subtree roots
  float* numG    = (float*)carve((size_t)85*GC*4);    // top internal
  float* epsG    = (float*)carve((size_t)341*GC*4);   // top + subtree-root eps
  unsigned int* sync_ = (unsigned int*)carve(512);    // [0] = arrival counter

  setup_kernel<<<18, 256, 0, stream>>>(a, b, pi, sp, a_sp, log_a, sm_bT, log_bT,
                                       sm_piT, log_piT, log_sp, sync_, out);
  uptop_kernel<<<256, 1024, 0, stream>>>(a_sp, log_a, log_sp, sm_bT, log_bT,
                                         sm_piT, t, betaG, numG, epsG, sync_, out);
  down_kernel<<<256, 1024, 0, stream>>>(a_sp, log_a, log_sp, sm_bT, log_bT,
                                        sm_piT, log_piT, t, epsG, out);
}

// Round 9
// 154.553 us; speedup vs baseline: 2.7280x; 1.1335x over previous
//
#include <hip/hip_runtime.h>

// Bottom-up HTMM on a complete 4-ary tree, depth 7 (t_size=21845).
// children(u)=4u+1..4u+4, pos(u)=(u-1)&3; only labels t[u*7] are data.
// prior cancels everywhere (only numbeta = prior*beta_il is used).
//
// THREE kernels, no cross-block waiting, no single-block serial tails:
//   setup   : softmaxes -> transposed tables, zero out.
//   up      : 256 blocks = 256 depth-3 subtrees in LDS; publish root betas.
//   downall : 256 blocks. Each redundantly recomputes the 85-node TOP in its
//             own LDS from the 256 published root betas, extracts its own
//             subtree-root eps via the unique 4-step root->subtree path;
//             block 0 alone also does the top-down likelihood contribution
//             (concurrent with other blocks, not a serial tail). Then
//             subtree-up redo + subtree-down + fused reduction.
// R8 bug fixed: top level-3 numbeta (nodes 21..84) is NEVER stored in sNum
// (sized 21*GC) — it is recomputed where needed (phase B: single ancestor;
// phase C: two-pass S/A accumulation). sNum indices are strictly 0..20.

#define G 16
#define C 8
#define GC 128
#define TSIZE 21845
#define SL 5461

__device__ __forceinline__ float grp8_sum(float v) {
  v += __shfl_xor(v, 1);
  v += __shfl_xor(v, 2);
  v += __shfl_xor(v, 4);
  return v;
}

// ---------------- setup: softmaxes + logs (transposed tables) -------------
__global__ void setup_kernel(const float* __restrict__ ain, const float* __restrict__ bin,
                             const float* __restrict__ piin, const float* __restrict__ spin,
                             float* __restrict__ a_sp, float* __restrict__ log_a,
                             float* __restrict__ sm_bT, float* __restrict__ log_bT,
                             float* __restrict__ sm_piT, float* __restrict__ log_piT,
                             float* __restrict__ log_sp, float* __restrict__ out) {
  int blk = blockIdx.x, tid = threadIdx.x;
  if (blk < 16) {
    // softmax over labels (M=256) for b[g][c][:]; write transposed [lab][g*8+c]
    int g = blk;
    __shared__ float red4[4];
    for (int c = 0; c < 8; ++c) {
      int row = g * 8 + c;
      float x = bin[row * 256 + tid];
      float m = x;
      #pragma unroll
      for (int off2 = 32; off2; off2 >>= 1) m = fmaxf(m, __shfl_xor(m, off2));
      if ((tid & 63) == 0) red4[tid >> 6] = m;
      __syncthreads();
      m = fmaxf(fmaxf(red4[0], red4[1]), fmaxf(red4[2], red4[3]));
      __syncthreads();
      float e = expf(x - m);
      float ssum = e;
      #pragma unroll
      for (int off2 = 32; off2; off2 >>= 1) ssum += __shfl_xor(ssum, off2);
      if ((tid & 63) == 0) red4[tid >> 6] = ssum;
      __syncthreads();
      ssum = red4[0] + red4[1] + red4[2] + red4[3];
      __syncthreads();
      sm_bT[tid * GC + row]  = e / ssum;
      log_bT[tid * GC + row] = (x - m) - logf(ssum);
    }
  } else if (blk == 16) {
    // softmax of a over i (axis=1), times sm_sp -> a_sp; also log(sm_a)
    for (int col = tid; col < 512; col += 256) {
      int g = col >> 5, j = (col >> 2) & 7, l = col & 3;
      float x[8], m = -1e30f;
      #pragma unroll
      for (int i = 0; i < 8; ++i) { x[i] = ain[g*256 + i*32 + j*4 + l]; m = fmaxf(m, x[i]); }
      float ssum = 0.f;
      #pragma unroll
      for (int i = 0; i < 8; ++i) ssum += expf(x[i] - m);
      float ls = logf(ssum);
      float y0 = spin[g*4+0], y1 = spin[g*4+1], y2 = spin[g*4+2], y3 = spin[g*4+3];
      float ms = fmaxf(fmaxf(y0, y1), fmaxf(y2, y3));
      float d = expf(y0-ms) + expf(y1-ms) + expf(y2-ms) + expf(y3-ms);
      float spv = expf(spin[g*4+l] - ms) / d;
      #pragma unroll
      for (int i = 0; i < 8; ++i) {
        int o2 = g*256 + i*32 + j*4 + l;
        float smv = expf(x[i] - m) / ssum;
        a_sp[o2]  = smv * spv;
        log_a[o2] = (x[i] - m) - ls;
      }
    }
  } else {
    if (tid < 64) {
      // softmax of pi over c (axis=1) for each (g,l); transposed [l][g*8+c]
      int g = tid >> 2, l = tid & 3;
      float x[8], m = -1e30f;
      #pragma unroll
      for (int c = 0; c < 8; ++c) { x[c] = piin[g*32 + c*4 + l]; m = fmaxf(m, x[c]); }
      float ssum = 0.f;
      #pragma unroll
      for (int c = 0; c < 8; ++c) ssum += expf(x[c] - m);
      float ls = logf(ssum);
      #pragma unroll
      for (int c = 0; c < 8; ++c) {
        sm_piT[l*GC + g*8 + c]  = expf(x[c] - m) / ssum;
        log_piT[l*GC + g*8 + c] = (x[c] - m) - ls;
      }
    } else if (tid < 80) {
      // log softmax of sp over l
      int g = tid - 64;
      float y[4], m = -1e30f;
      #pragma unroll
      for (int l = 0; l < 4; ++l) { y[l] = spin[g*4 + l]; m = fmaxf(m, y[l]); }
      float ssum = 0.f;
      #pragma unroll
      for (int l = 0; l < 4; ++l) ssum += expf(y[l] - m);
      float ls = logf(ssum);
      #pragma unroll
      for (int l = 0; l < 4; ++l) log_sp[g*4 + l] = (y[l] - m) - ls;
    } else if (tid < 96) {
      out[tid - 80] = 0.0f;        // zero the accumulator (poisoned 0xAA)
    }
  }
}

// ---------------- LDS bodies (validated rounds 4/5/7) ---------------------
__device__ __forceinline__ void up_lds(int v, int lab, int gi, int g8,
    const float* asp, const float* __restrict__ sm_bT,
    float* sBeta, float* sNum, bool wantNum) {
  int ch0 = 4*v + 1;
  float ub = 0.f;
  #pragma unroll
  for (int l = 0; l < 4; ++l) {
    const float4* bp = (const float4*)(sBeta + (ch0 + l)*GC + g8);
    float4 b0 = bp[0], b1 = bp[1];
    ub += asp[l]*b0.x + asp[4+l]*b0.y + asp[8+l]*b0.z + asp[12+l]*b0.w
        + asp[16+l]*b1.x + asp[20+l]*b1.y + asp[24+l]*b1.z + asp[28+l]*b1.w;
  }
  float tmp = sm_bT[lab*GC + gi] * ub;
  float s = grp8_sum(tmp);
  sBeta[v*GC + gi] = tmp / s;
  if (wantNum) sNum[v*GC + gi] = ub;
}

__device__ __forceinline__ double down_lds(int v, int lab, float e, int gi, int g8,
    const float* asp, const float* aal, const float* lsp,
    const float* __restrict__ log_bT, float* sBeta, const float* sNum) {
  float pe = e / sNum[v*GC + gi];
  int ch0 = 4*v + 1;
  float local = 0.f;
  #pragma unroll
  for (int l = 0; l < 4; ++l) {
    float4* bp = (float4*)(sBeta + (ch0 + l)*GC + g8);
    float4 b0 = bp[0], b1 = bp[1];
    float S = asp[l]*b0.x + asp[4+l]*b0.y + asp[8+l]*b0.z + asp[12+l]*b0.w
            + asp[16+l]*b1.x + asp[20+l]*b1.y + asp[24+l]*b1.z + asp[28+l]*b1.w;
    float A = aal[l]*b0.x + aal[4+l]*b0.y + aal[8+l]*b0.z + aal[12+l]*b0.w
            + aal[16+l]*b1.x + aal[20+l]*b1.y + aal[24+l]*b1.z + aal[28+l]*b1.w;
    float ce = pe * S;
    sBeta[(ch0 + l)*GC + gi] = ce;          // beta slot -> eps
    local += pe*A + ce*lsp[l];
  }
  return (double)local + (double)(e * log_bT[lab*GC + gi]);
}

// ---------------- up: 256 subtrees in LDS, write only root betas ----------
__global__ __launch_bounds__(1024, 1) void up_kernel(
    const float* __restrict__ a_sp, const float* __restrict__ sm_bT,
    const float* __restrict__ sm_piT, const int* __restrict__ t,
    float* __restrict__ betaG) {
  __shared__ float sBeta[85*GC];            // 42.5 KB
  const int blk = blockIdx.x, tid = threadIdx.x;
  const int gi = tid & 127, g = gi >> 3, i = gi & 7, g8 = g*8, w = tid >> 7;
  float asp[32];
  {
    const float4* pa = (const float4*)(a_sp + g*256 + i*32);
    #pragma unroll
    for (int q = 0; q < 8; ++q) {
      float4 v = pa[q];
      asp[q*4+0]=v.x; asp[q*4+1]=v.y; asp[q*4+2]=v.z; asp[q*4+3]=v.w;
    }
  }
  const int base_leaf = SL + blk*64;
  #pragma unroll
  for (int it = 0; it < 8; ++it) {          // leaves: locals 21..84
    int k = it*8 + w;
    float bt = sm_piT[(k & 3)*GC + gi] * sm_bT[t[(base_leaf + k)*7]*GC + gi];
    float s = grp8_sum(bt);
    sBeta[(21 + k)*GC + gi] = bt / s;
  }
  __syncthreads();
  #pragma unroll
  for (int it = 0; it < 2; ++it) {          // level 6: locals 5..20
    int k = it*8 + w;
    up_lds(5 + k, t[(1365 + blk*16 + k)*7], gi, g8, asp, sm_bT, sBeta, nullptr, false);
  }
  __syncthreads();
  if (tid < 512)                            // level 5: locals 1..4
    up_lds(1 + w, t[(341 + blk*4 + w)*7], gi, g8, asp, sm_bT, sBeta, nullptr, false);
  __syncthreads();
  if (tid < 128) {                          // subtree root: local 0
    up_lds(0, t[(85 + blk)*7], gi, g8, asp, sm_bT, sBeta, nullptr, false);
    betaG[(size_t)(85 + blk)*GC + gi] = sBeta[gi];   // plain store; boundary flushes
  }
}

// ---------------- downall: redundant top + own path + subtree down --------
__global__ __launch_bounds__(1024, 1) void downall_kernel(
    const float* __restrict__ a_sp, const float* __restrict__ log_a,
    const float* __restrict__ log_sp, const float* __restrict__ sm_bT,
    const float* __restrict__ log_bT, const float* __restrict__ sm_piT,
    const float* __restrict__ log_piT, const int* __restrict__ t,
    const float* __restrict__ betaG, float* __restrict__ out) {
  __shared__ float  sBeta[85*GC];           // top first, then subtree (42.5 KB)
  __shared__ float  sNum[21*GC];            // ids 0..20 ONLY (10.5 KB)
  __shared__ float  sEps[GC];               // own subtree-root eps
  __shared__ double sd[128];
  const int blk = blockIdx.x, tid = threadIdx.x;
  const int gi = tid & 127, g = gi >> 3, i = gi & 7, g8 = g*8, w = tid >> 7;
  float asp[32], aal[32], lsp[4];
  {
    const float4* pa = (const float4*)(a_sp  + g*256 + i*32);
    const float4* pl = (const float4*)(log_a + g*256 + i*32);
    #pragma unroll
    for (int k = 0; k < 8; ++k) {
      float4 va = pa[k], vl = pl[k];
      asp[k*4+0]=va.x; asp[k*4+1]=va.y; asp[k*4+2]=va.z; asp[k*4+3]=va.w;
      aal[k*4+0]=va.x*vl.x; aal[k*4+1]=va.y*vl.y; aal[k*4+2]=va.z*vl.z; aal[k*4+3]=va.w*vl.w;
    }
    #pragma unroll
    for (int l = 0; l < 4; ++l) lsp[l] = log_sp[g*4 + l];
  }

  // ===== phase A: top-up in LDS (nodes 0..84; node id == LDS slot) =====
  #pragma unroll
  for (int it = 0; it < 8; ++it) {          // level 3: 64 nodes, global children
    int k = it*8 + w, u = 21 + k;
    int ch0 = 4*u + 1;                      // = 85 + 4k (subtree roots)
    float ub = 0.f;
    #pragma unroll
    for (int l = 0; l < 4; ++l) {
      const float4* bp = (const float4*)(betaG + (size_t)(ch0 + l)*GC + g8);
      float4 b0 = bp[0], b1 = bp[1];
      ub += asp[l]*b0.x + asp[4+l]*b0.y + asp[8+l]*b0.z + asp[12+l]*b0.w
          + asp[16+l]*b1.x + asp[20+l]*b1.y + asp[24+l]*b1.z + asp[28+l]*b1.w;
    }
    float tmp = sm_bT[t[u*7]*GC + gi] * ub;
    float s = grp8_sum(tmp);
    sBeta[u*GC + gi] = tmp / s;             // numbeta for 21..84 NOT stored
  }
  __syncthreads();
  #pragma unroll
  for (int it = 0; it < 2; ++it) {          // level 2: nodes 5..20
    int u = 5 + it*8 + w;
    up_lds(u, t[u*7], gi, g8, asp, sm_bT, sBeta, sNum, true);
  }
  __syncthreads();
  if (tid < 512)                            // level 1: nodes 1..4
    up_lds(1 + w, t[(1 + w)*7], gi, g8, asp, sm_bT, sBeta, sNum, true);
  __syncthreads();
  if (tid < 128)                            // root
    up_lds(0, t[0], gi, g8, asp, sm_bT, sBeta, sNum, true);
  __syncthreads();

  // ===== phase B: own subtree-root eps via the 4-step root path =====
  if (tid < 128) {
    int a1 = 1 + (blk >> 6), a2 = 5 + (blk >> 4), a3 = 21 + (blk >> 2);
    float e = sBeta[gi];                    // eps(root) = beta(root)
    int anc[3] = {0, a1, a2};
    int chn[3] = {a1, a2, a3};
    #pragma unroll
    for (int s2 = 0; s2 < 3; ++s2) {        // anc ids 0..20: sNum valid
      float pe = e / sNum[anc[s2]*GC + gi];
      int l = (chn[s2] - 1) & 3;
      const float4* bp = (const float4*)(sBeta + chn[s2]*GC + g8);
      float4 b0 = bp[0], b1 = bp[1];
      float S = asp[l]*b0.x + asp[4+l]*b0.y + asp[8+l]*b0.z + asp[12+l]*b0.w
              + asp[16+l]*b1.x + asp[20+l]*b1.y + asp[24+l]*b1.z + asp[28+l]*b1.w;
      e = pe * S;
    }
    {   // final step a3 -> own root (85+blk): recompute num(a3) from betaG
      float num3 = 0.f;
      int c30 = 4*a3 + 1;                   // children of a3 (global 85..340)
      #pragma unroll
      for (int l = 0; l < 4; ++l) {
        const float4* bp = (const float4*)(betaG + (size_t)(c30 + l)*GC + g8);
        float4 b0 = bp[0], b1 = bp[1];
        num3 += asp[l]*b0.x + asp[4+l]*b0.y + asp[8+l]*b0.z + asp[12+l]*b0.w
              + asp[16+l]*b1.x + asp[20+l]*b1.y + asp[24+l]*b1.z + asp[28+l]*b1.w;
      }
      float pe = e / num3;
      int l = blk & 3;
      const float4* bp = (const float4*)(betaG + (size_t)(85 + blk)*GC + g8);
      float4 b0 = bp[0], b1 = bp[1];
      float S = asp[l]*b0.x + asp[4+l]*b0.y + asp[8+l]*b0.z + asp[12+l]*b0.w
              + asp[16+l]*b1.x + asp[20+l]*b1.y + asp[24+l]*b1.z + asp[28+l]*b1.w;
      e = pe * S;
    }
    sEps[gi] = e;
  }
  __syncthreads();

  // ===== phase C: block 0 only — full top-down + top contribution =====
  if (blk == 0) {
    double acc0 = 0.0;
    if (tid < 128)
      acc0 += down_lds(0, t[0], sBeta[gi], gi, g8, asp, aal, lsp, log_bT, sBeta, sNum);
    __syncthreads();
    if (tid < 512) {
      int v = 1 + w;
      acc0 += down_lds(v, t[v*7], sBeta[v*GC + gi], gi, g8, asp, aal, lsp, log_bT, sBeta, sNum);
    }
    __syncthreads();
    #pragma unroll
    for (int it = 0; it < 2; ++it) {
      int v = 5 + it*8 + w;
      acc0 += down_lds(v, t[v*7], sBeta[v*GC + gi], gi, g8, asp, aal, lsp, log_bT, sBeta, sNum);
    }
    __syncthreads();
    #pragma unroll
    for (int it = 0; it < 8; ++it) {        // level 3: contribution only;
      int k = it*8 + w, u = 21 + k;         // num recomputed two-pass
      float e = sBeta[u*GC + gi];           // eps (written by level-2 step)
      int ch0 = 4*u + 1;
      float Sv[4], Av[4], num = 0.f;
      #pragma unroll
      for (int l = 0; l < 4; ++l) {
        const float4* bp = (const float4*)(betaG + (size_t)(ch0 + l)*GC + g8);
        float4 b0 = bp[0], b1 = bp[1];
        Sv[l] = asp[l]*b0.x + asp[4+l]*b0.y + asp[8+l]*b0.z + asp[12+l]*b0.w
              + asp[16+l]*b1.x + asp[20+l]*b1.y + asp[24+l]*b1.z + asp[28+l]*b1.w;
        Av[l] = aal[l]*b0.x + aal[4+l]*b0.y + aal[8+l]*b0.z + aal[12+l]*b0.w
              + aal[16+l]*b1.x + aal[20+l]*b1.y + aal[24+l]*b1.z + aal[28+l]*b1.w;
        num += Sv[l];
      }
      float pe = e / num;
      float local = 0.f;
      #pragma unroll
      for (int l = 0; l < 4; ++l) {
        float ce = pe * Sv[l];
        local += pe*Av[l] + ce*lsp[l];
      }
      acc0 += (double)local + (double)(e * log_bT[t[u*7]*GC + gi]);
    }
    acc0 += __shfl_xor(acc0, 1);
    acc0 += __shfl_xor(acc0, 2);
    acc0 += __shfl_xor(acc0, 4);
    if (i == 0) sd[tid >> 3] = acc0;
    __syncthreads();
    if (tid < 16) {
      double s = 0.0;
      #pragma unroll
      for (int c2 = 0; c2 < 8; ++c2) s += sd[tid + 16*c2];
      atomicAdd(&out[tid], (float)s);
    }
    __syncthreads();                        // protect sd/sBeta reuse below
  }

  // ===== phase D: subtree-up redo (overwrites sBeta/sNum) =====
  const int base_leaf = SL + blk*64;
  #pragma unroll
  for (int it = 0; it < 8; ++it) {
    int k = it*8 + w;
    float bt = sm_piT[(k & 3)*GC + gi] * sm_bT[t[(base_leaf + k)*7]*GC + gi];
    float s = grp8_sum(bt);
    sBeta[(21 + k)*GC + gi] = bt / s;
  }
  __syncthreads();
  #pragma unroll
  for (int it = 0; it < 2; ++it) {
    int k = it*8 + w;
    up_lds(5 + k, t[(1365 + blk*16 + k)*7], gi, g8, asp, sm_bT, sBeta, sNum, true);
  }
  __syncthreads();
  if (tid < 512)
    up_lds(1 + w, t[(341 + blk*4 + w)*7], gi, g8, asp, sm_bT, sBeta, sNum, true);
  __syncthreads();

  // ===== phase E: subtree down + fused reduction =====
  double acc = 0.0;
  if (tid < 128) {
    up_lds(0, t[(85 + blk)*7], gi, g8, asp, sm_bT, sBeta, sNum, true);   // root numbeta
    acc += down_lds(0, t[(85 + blk)*7], sEps[gi], gi, g8, asp, aal, lsp,
                    log_bT, sBeta, sNum);
  }
  __syncthreads();
  if (tid < 512) {                          // level 5 (locals 1..4)
    int v = 1 + w;
    acc += down_lds(v, t[(341 + blk*4 + w)*7], sBeta[v*GC + gi], gi, g8,
                    asp, aal, lsp, log_bT, sBeta, sNum);
  }
  __syncthreads();
  #pragma unroll
  for (int it = 0; it < 2; ++it) {          // level 6 (locals 5..20)
    int k = it*8 + w, v = 5 + k;
    acc += down_lds(v, t[(1365 + blk*16 + k)*7], sBeta[v*GC + gi], gi, g8,
                    asp, aal, lsp, log_bT, sBeta, sNum);
  }
  __syncthreads();
  #pragma unroll
  for (int it = 0; it < 8; ++it) {          // leaves: b_lh + pi_lh
    int k = it*8 + w;
    float e = sBeta[(21 + k)*GC + gi];
    acc += (double)(e * (log_bT[t[(base_leaf + k)*7]*GC + gi] +
                         log_piT[(k & 3)*GC + gi]));
  }
  acc += __shfl_xor(acc, 1);
  acc += __shfl_xor(acc, 2);
  acc += __shfl_xor(acc, 4);
  if (i == 0) sd[tid >> 3] = acc;           // tid>>3 = w*16 + g
  __syncthreads();
  if (tid < 16) {
    double s = 0.0;
    #pragma unroll
    for (int c2 = 0; c2 < 8; ++c2) s += sd[tid + 16*c2];
    atomicAdd(&out[tid], (float)s);
  }
}

extern "C" void kernel_launch(void* const* d_in, const int* in_sizes, int n_in,
                              void* d_out, int out_size, void* d_ws, size_t ws_size,
                              hipStream_t stream) {
  const int*   t  = (const int*)d_in[0];
  // d_in[1] = t_limits (tree shape is compile-time constant)
  const float* a  = (const float*)d_in[2];
  const float* b  = (const float*)d_in[3];
  const float* pi = (const float*)d_in[4];
  const float* sp = (const float*)d_in[5];
  float* out = (float*)d_out;

  char* w = (char*)d_ws;
  size_t off = 0;
  auto carve = [&](size_t bytes) -> void* {
    void* ptr = w + off;
    off += (bytes + 255) & ~(size_t)255;
    return ptr;
  };
  float* a_sp    = (float*)carve((size_t)16*8*8*4*4);
  float* log_a   = (float*)carve((size_t)16*8*8*4*4);
  float* sm_bT   = (float*)carve((size_t)256*GC*4);
  float* log_bT  = (float*)carve((size_t)256*GC*4);
  float* sm_piT  = (float*)carve((size_t)4*GC*4);
  float* log_piT = (float*)carve((size_t)4*GC*4);
  float* log_sp  = (float*)carve((size_t)16*4*4);
  float* betaG   = (float*)carve((size_t)341*GC*4);   // subtree-root betas

  setup_kernel<<<18, 256, 0, stream>>>(a, b, pi, sp, a_sp, log_a, sm_bT, log_bT,
                                       sm_piT, log_piT, log_sp, out);
  up_kernel<<<256, 1024, 0, stream>>>(a_sp, sm_bT, sm_piT, t, betaG);
  downall_kernel<<<256, 1024, 0, stream>>>(a_sp, log_a, log_sp, sm_bT, log_bT,
                                           sm_piT, log_piT, t, betaG, out);
}

// Round 10
// 115.071 us; speedup vs baseline: 3.6640x; 1.3431x over previous
//
#include <hip/hip_runtime.h>

// Bottom-up HTMM on a complete 4-ary tree, depth 7 (t_size=21845).
// children(u)=4u+1..4u+4, pos(u)=(u-1)&3; only labels t[u*7] are data.
// prior cancels everywhere (only numbeta = prior*beta_il is used).
//
// THREE kernels, no cross-block waiting, no single-block serial tails.
// R9 lesson (rocprof): 1024-thread blocks get a 64-VGPR cap -> asp/aal
// (68 floats/thread) spill to scratch = 72 MB/dispatch of WRITE traffic.
// 512-thread blocks get ~128 VGPRs (R4: VGPR_Count=124) -> no spill.
//   setup   : softmaxes -> transposed tables, zero out.
//   up      : 256 blocks x 512 = 256 depth-3 subtrees in LDS; publish root betas.
//   downall : 256 blocks x 512. Each redundantly recomputes the 85-node TOP
//             in its own LDS from the published root betas, extracts its own
//             subtree-root eps via the unique root->subtree path; block 0
//             also does the top-down contribution (concurrent). Then
//             subtree-up redo + subtree-down + fused reduction.
// sNum holds ids 0..20 ONLY; top level-3 numbeta is recomputed where needed.

#define G 16
#define C 8
#define GC 128
#define TSIZE 21845
#define SL 5461

__device__ __forceinline__ float grp8_sum(float v) {
  v += __shfl_xor(v, 1);
  v += __shfl_xor(v, 2);
  v += __shfl_xor(v, 4);
  return v;
}

// ---------------- setup: softmaxes + logs (transposed tables) -------------
__global__ void setup_kernel(const float* __restrict__ ain, const float* __restrict__ bin,
                             const float* __restrict__ piin, const float* __restrict__ spin,
                             float* __restrict__ a_sp, float* __restrict__ log_a,
                             float* __restrict__ sm_bT, float* __restrict__ log_bT,
                             float* __restrict__ sm_piT, float* __restrict__ log_piT,
                             float* __restrict__ log_sp, float* __restrict__ out) {
  int blk = blockIdx.x, tid = threadIdx.x;
  if (blk < 16) {
    // softmax over labels (M=256) for b[g][c][:]; write transposed [lab][g*8+c]
    int g = blk;
    __shared__ float red4[4];
    for (int c = 0; c < 8; ++c) {
      int row = g * 8 + c;
      float x = bin[row * 256 + tid];
      float m = x;
      #pragma unroll
      for (int off2 = 32; off2; off2 >>= 1) m = fmaxf(m, __shfl_xor(m, off2));
      if ((tid & 63) == 0) red4[tid >> 6] = m;
      __syncthreads();
      m = fmaxf(fmaxf(red4[0], red4[1]), fmaxf(red4[2], red4[3]));
      __syncthreads();
      float e = expf(x - m);
      float ssum = e;
      #pragma unroll
      for (int off2 = 32; off2; off2 >>= 1) ssum += __shfl_xor(ssum, off2);
      if ((tid & 63) == 0) red4[tid >> 6] = ssum;
      __syncthreads();
      ssum = red4[0] + red4[1] + red4[2] + red4[3];
      __syncthreads();
      sm_bT[tid * GC + row]  = e / ssum;
      log_bT[tid * GC + row] = (x - m) - logf(ssum);
    }
  } else if (blk == 16) {
    // softmax of a over i (axis=1), times sm_sp -> a_sp; also log(sm_a)
    for (int col = tid; col < 512; col += 256) {
      int g = col >> 5, j = (col >> 2) & 7, l = col & 3;
      float x[8], m = -1e30f;
      #pragma unroll
      for (int i = 0; i < 8; ++i) { x[i] = ain[g*256 + i*32 + j*4 + l]; m = fmaxf(m, x[i]); }
      float ssum = 0.f;
      #pragma unroll
      for (int i = 0; i < 8; ++i) ssum += expf(x[i] - m);
      float ls = logf(ssum);
      float y0 = spin[g*4+0], y1 = spin[g*4+1], y2 = spin[g*4+2], y3 = spin[g*4+3];
      float ms = fmaxf(fmaxf(y0, y1), fmaxf(y2, y3));
      float d = expf(y0-ms) + expf(y1-ms) + expf(y2-ms) + expf(y3-ms);
      float spv = expf(spin[g*4+l] - ms) / d;
      #pragma unroll
      for (int i = 0; i < 8; ++i) {
        int o2 = g*256 + i*32 + j*4 + l;
        float smv = expf(x[i] - m) / ssum;
        a_sp[o2]  = smv * spv;
        log_a[o2] = (x[i] - m) - ls;
      }
    }
  } else {
    if (tid < 64) {
      // softmax of pi over c (axis=1) for each (g,l); transposed [l][g*8+c]
      int g = tid >> 2, l = tid & 3;
      float x[8], m = -1e30f;
      #pragma unroll
      for (int c = 0; c < 8; ++c) { x[c] = piin[g*32 + c*4 + l]; m = fmaxf(m, x[c]); }
      float ssum = 0.f;
      #pragma unroll
      for (int c = 0; c < 8; ++c) ssum += expf(x[c] - m);
      float ls = logf(ssum);
      #pragma unroll
      for (int c = 0; c < 8; ++c) {
        sm_piT[l*GC + g*8 + c]  = expf(x[c] - m) / ssum;
        log_piT[l*GC + g*8 + c] = (x[c] - m) - ls;
      }
    } else if (tid < 80) {
      // log softmax of sp over l
      int g = tid - 64;
      float y[4], m = -1e30f;
      #pragma unroll
      for (int l = 0; l < 4; ++l) { y[l] = spin[g*4 + l]; m = fmaxf(m, y[l]); }
      float ssum = 0.f;
      #pragma unroll
      for (int l = 0; l < 4; ++l) ssum += expf(y[l] - m);
      float ls = logf(ssum);
      #pragma unroll
      for (int l = 0; l < 4; ++l) log_sp[g*4 + l] = (y[l] - m) - ls;
    } else if (tid < 96) {
      out[tid - 80] = 0.0f;        // zero the accumulator (poisoned 0xAA)
    }
  }
}

// ---------------- LDS bodies (validated rounds 4/5/7/9) -------------------
__device__ __forceinline__ void up_lds(int v, int lab, int gi, int g8,
    const float* asp, const float* __restrict__ sm_bT,
    float* sBeta, float* sNum, bool wantNum) {
  int ch0 = 4*v + 1;
  float ub = 0.f;
  #pragma unroll
  for (int l = 0; l < 4; ++l) {
    const float4* bp = (const float4*)(sBeta + (ch0 + l)*GC + g8);
    float4 b0 = bp[0], b1 = bp[1];
    ub += asp[l]*b0.x + asp[4+l]*b0.y + asp[8+l]*b0.z + asp[12+l]*b0.w
        + asp[16+l]*b1.x + asp[20+l]*b1.y + asp[24+l]*b1.z + asp[28+l]*b1.w;
  }
  float tmp = sm_bT[lab*GC + gi] * ub;
  float s = grp8_sum(tmp);
  sBeta[v*GC + gi] = tmp / s;
  if (wantNum) sNum[v*GC + gi] = ub;
}

__device__ __forceinline__ double down_lds(int v, int lab, float e, int gi, int g8,
    const float* asp, const float* aal, const float* lsp,
    const float* __restrict__ log_bT, float* sBeta, const float* sNum) {
  float pe = e / sNum[v*GC + gi];
  int ch0 = 4*v + 1;
  float local = 0.f;
  #pragma unroll
  for (int l = 0; l < 4; ++l) {
    float4* bp = (float4*)(sBeta + (ch0 + l)*GC + g8);
    float4 b0 = bp[0], b1 = bp[1];
    float S = asp[l]*b0.x + asp[4+l]*b0.y + asp[8+l]*b0.z + asp[12+l]*b0.w
            + asp[16+l]*b1.x + asp[20+l]*b1.y + asp[24+l]*b1.z + asp[28+l]*b1.w;
    float A = aal[l]*b0.x + aal[4+l]*b0.y + aal[8+l]*b0.z + aal[12+l]*b0.w
            + aal[16+l]*b1.x + aal[20+l]*b1.y + aal[24+l]*b1.z + aal[28+l]*b1.w;
    float ce = pe * S;
    sBeta[(ch0 + l)*GC + gi] = ce;          // beta slot -> eps
    local += pe*A + ce*lsp[l];
  }
  return (double)local + (double)(e * log_bT[lab*GC + gi]);
}

// ---------------- up: 256 subtrees in LDS, write only root betas ----------
__global__ __launch_bounds__(512, 1) void up_kernel(
    const float* __restrict__ a_sp, const float* __restrict__ sm_bT,
    const float* __restrict__ sm_piT, const int* __restrict__ t,
    float* __restrict__ betaG) {
  __shared__ float sBeta[85*GC];            // 42.5 KB
  const int blk = blockIdx.x, tid = threadIdx.x;
  const int gi = tid & 127, g = gi >> 3, i = gi & 7, g8 = g*8, w = tid >> 7; // w 0..3
  float asp[32];
  {
    const float4* pa = (const float4*)(a_sp + g*256 + i*32);
    #pragma unroll
    for (int q = 0; q < 8; ++q) {
      float4 v = pa[q];
      asp[q*4+0]=v.x; asp[q*4+1]=v.y; asp[q*4+2]=v.z; asp[q*4+3]=v.w;
    }
  }
  const int base_leaf = SL + blk*64;
  #pragma unroll
  for (int it = 0; it < 16; ++it) {         // leaves: locals 21..84
    int k = it*4 + w;
    float bt = sm_piT[(k & 3)*GC + gi] * sm_bT[t[(base_leaf + k)*7]*GC + gi];
    float s = grp8_sum(bt);
    sBeta[(21 + k)*GC + gi] = bt / s;
  }
  __syncthreads();
  #pragma unroll
  for (int it = 0; it < 4; ++it) {          // level 6: locals 5..20
    int k = it*4 + w;
    up_lds(5 + k, t[(1365 + blk*16 + k)*7], gi, g8, asp, sm_bT, sBeta, nullptr, false);
  }
  __syncthreads();
  up_lds(1 + w, t[(341 + blk*4 + w)*7], gi, g8, asp, sm_bT, sBeta, nullptr, false); // lvl5
  __syncthreads();
  if (tid < 128) {                          // subtree root: local 0
    up_lds(0, t[(85 + blk)*7], gi, g8, asp, sm_bT, sBeta, nullptr, false);
    betaG[(size_t)(85 + blk)*GC + gi] = sBeta[gi];   // plain store; boundary flushes
  }
}

// ---------------- downall: redundant top + own path + subtree down --------
__global__ __launch_bounds__(512, 1) void downall_kernel(
    const float* __restrict__ a_sp, const float* __restrict__ log_a,
    const float* __restrict__ log_sp, const float* __restrict__ sm_bT,
    const float* __restrict__ log_bT, const float* __restrict__ sm_piT,
    const float* __restrict__ log_piT, const int* __restrict__ t,
    const float* __restrict__ betaG, float* __restrict__ out) {
  __shared__ float  sBeta[85*GC];           // top first, then subtree (42.5 KB)
  __shared__ float  sNum[21*GC];            // ids 0..20 ONLY (10.5 KB)
  __shared__ float  sEps[GC];               // own subtree-root eps
  __shared__ double sd[64];
  const int blk = blockIdx.x, tid = threadIdx.x;
  const int gi = tid & 127, g = gi >> 3, i = gi & 7, g8 = g*8, w = tid >> 7; // w 0..3
  float asp[32], aal[32], lsp[4];
  {
    const float4* pa = (const float4*)(a_sp  + g*256 + i*32);
    const float4* pl = (const float4*)(log_a + g*256 + i*32);
    #pragma unroll
    for (int k = 0; k < 8; ++k) {
      float4 va = pa[k], vl = pl[k];
      asp[k*4+0]=va.x; asp[k*4+1]=va.y; asp[k*4+2]=va.z; asp[k*4+3]=va.w;
      aal[k*4+0]=va.x*vl.x; aal[k*4+1]=va.y*vl.y; aal[k*4+2]=va.z*vl.z; aal[k*4+3]=va.w*vl.w;
    }
    #pragma unroll
    for (int l = 0; l < 4; ++l) lsp[l] = log_sp[g*4 + l];
  }

  // ===== phase A: top-up in LDS (nodes 0..84; node id == LDS slot) =====
  #pragma unroll
  for (int it = 0; it < 16; ++it) {         // level 3: 64 nodes, global children
    int k = it*4 + w, u = 21 + k;
    int ch0 = 4*u + 1;                      // = 85 + 4k (subtree roots)
    float ub = 0.f;
    #pragma unroll
    for (int l = 0; l < 4; ++l) {
      const float4* bp = (const float4*)(betaG + (size_t)(ch0 + l)*GC + g8);
      float4 b0 = bp[0], b1 = bp[1];
      ub += asp[l]*b0.x + asp[4+l]*b0.y + asp[8+l]*b0.z + asp[12+l]*b0.w
          + asp[16+l]*b1.x + asp[20+l]*b1.y + asp[24+l]*b1.z + asp[28+l]*b1.w;
    }
    float tmp = sm_bT[t[u*7]*GC + gi] * ub;
    float s = grp8_sum(tmp);
    sBeta[u*GC + gi] = tmp / s;             // numbeta for 21..84 NOT stored
  }
  __syncthreads();
  #pragma unroll
  for (int it = 0; it < 4; ++it) {          // level 2: nodes 5..20
    int u = 5 + it*4 + w;
    up_lds(u, t[u*7], gi, g8, asp, sm_bT, sBeta, sNum, true);
  }
  __syncthreads();
  up_lds(1 + w, t[(1 + w)*7], gi, g8, asp, sm_bT, sBeta, sNum, true);   // lvl1
  __syncthreads();
  if (tid < 128)                            // root
    up_lds(0, t[0], gi, g8, asp, sm_bT, sBeta, sNum, true);
  __syncthreads();

  // ===== phase B: own subtree-root eps via the 4-step root path =====
  if (tid < 128) {
    int a1 = 1 + (blk >> 6), a2 = 5 + (blk >> 4), a3 = 21 + (blk >> 2);
    float e = sBeta[gi];                    // eps(root) = beta(root)
    int anc[3] = {0, a1, a2};
    int chn[3] = {a1, a2, a3};
    #pragma unroll
    for (int s2 = 0; s2 < 3; ++s2) {        // anc ids 0..20: sNum valid
      float pe = e / sNum[anc[s2]*GC + gi];
      int l = (chn[s2] - 1) & 3;
      const float4* bp = (const float4*)(sBeta + chn[s2]*GC + g8);
      float4 b0 = bp[0], b1 = bp[1];
      float S = asp[l]*b0.x + asp[4+l]*b0.y + asp[8+l]*b0.z + asp[12+l]*b0.w
              + asp[16+l]*b1.x + asp[20+l]*b1.y + asp[24+l]*b1.z + asp[28+l]*b1.w;
      e = pe * S;
    }
    {   // final step a3 -> own root (85+blk): recompute num(a3) from betaG
      float num3 = 0.f;
      int c30 = 4*a3 + 1;                   // children of a3 (global 85..340)
      #pragma unroll
      for (int l = 0; l < 4; ++l) {
        const float4* bp = (const float4*)(betaG + (size_t)(c30 + l)*GC + g8);
        float4 b0 = bp[0], b1 = bp[1];
        num3 += asp[l]*b0.x + asp[4+l]*b0.y + asp[8+l]*b0.z + asp[12+l]*b0.w
              + asp[16+l]*b1.x + asp[20+l]*b1.y + asp[24+l]*b1.z + asp[28+l]*b1.w;
      }
      float pe = e / num3;
      int l = blk & 3;
      const float4* bp = (const float4*)(betaG + (size_t)(85 + blk)*GC + g8);
      float4 b0 = bp[0], b1 = bp[1];
      float S = asp[l]*b0.x + asp[4+l]*b0.y + asp[8+l]*b0.z + asp[12+l]*b0.w
              + asp[16+l]*b1.x + asp[20+l]*b1.y + asp[24+l]*b1.z + asp[28+l]*b1.w;
      e = pe * S;
    }
    sEps[gi] = e;
  }
  __syncthreads();

  // ===== phase C: block 0 only — full top-down + top contribution =====
  if (blk == 0) {
    double acc0 = 0.0;
    if (tid < 128)
      acc0 += down_lds(0, t[0], sBeta[gi], gi, g8, asp, aal, lsp, log_bT, sBeta, sNum);
    __syncthreads();
    {
      int v = 1 + w;
      acc0 += down_lds(v, t[v*7], sBeta[v*GC + gi], gi, g8, asp, aal, lsp, log_bT, sBeta, sNum);
    }
    __syncthreads();
    #pragma unroll
    for (int it = 0; it < 4; ++it) {
      int v = 5 + it*4 + w;
      acc0 += down_lds(v, t[v*7], sBeta[v*GC + gi], gi, g8, asp, aal, lsp, log_bT, sBeta, sNum);
    }
    __syncthreads();
    #pragma unroll
    for (int it = 0; it < 16; ++it) {       // level 3: contribution only;
      int k = it*4 + w, u = 21 + k;         // num recomputed two-pass
      float e = sBeta[u*GC + gi];           // eps (written by level-2 step)
      int ch0 = 4*u + 1;
      float Sv[4], Av[4], num = 0.f;
      #pragma unroll
      for (int l = 0; l < 4; ++l) {
        const float4* bp = (const float4*)(betaG + (size_t)(ch0 + l)*GC + g8);
        float4 b0 = bp[0], b1 = bp[1];
        Sv[l] = asp[l]*b0.x + asp[4+l]*b0.y + asp[8+l]*b0.z + asp[12+l]*b0.w
              + asp[16+l]*b1.x + asp[20+l]*b1.y + asp[24+l]*b1.z + asp[28+l]*b1.w;
        Av[l] = aal[l]*b0.x + aal[4+l]*b0.y + aal[8+l]*b0.z + aal[12+l]*b0.w
              + aal[16+l]*b1.x + aal[20+l]*b1.y + aal[24+l]*b1.z + aal[28+l]*b1.w;
        num += Sv[l];
      }
      float pe = e / num;
      float local = 0.f;
      #pragma unroll
      for (int l = 0; l < 4; ++l) {
        float ce = pe * Sv[l];
        local += pe*Av[l] + ce*lsp[l];
      }
      acc0 += (double)local + (double)(e * log_bT[t[u*7]*GC + gi]);
    }
    acc0 += __shfl_xor(acc0, 1);
    acc0 += __shfl_xor(acc0, 2);
    acc0 += __shfl_xor(acc0, 4);
    if (i == 0) sd[tid >> 3] = acc0;        // tid>>3 = w*16 + g  (0..63)
    __syncthreads();
    if (tid < 16) {
      double s = sd[tid] + sd[16 + tid] + sd[32 + tid] + sd[48 + tid];
      atomicAdd(&out[tid], (float)s);
    }
    __syncthreads();                        // protect sd/sBeta reuse below
  }

  // ===== phase D: subtree-up redo (overwrites sBeta/sNum) =====
  const int base_leaf = SL + blk*64;
  #pragma unroll
  for (int it = 0; it < 16; ++it) {
    int k = it*4 + w;
    float bt = sm_piT[(k & 3)*GC + gi] * sm_bT[t[(base_leaf + k)*7]*GC + gi];
    float s = grp8_sum(bt);
    sBeta[(21 + k)*GC + gi] = bt / s;
  }
  __syncthreads();
  #pragma unroll
  for (int it = 0; it < 4; ++it) {
    int k = it*4 + w;
    up_lds(5 + k, t[(1365 + blk*16 + k)*7], gi, g8, asp, sm_bT, sBeta, sNum, true);
  }
  __syncthreads();
  up_lds(1 + w, t[(341 + blk*4 + w)*7], gi, g8, asp, sm_bT, sBeta, sNum, true);  // lvl5
  __syncthreads();

  // ===== phase E: subtree down + fused reduction =====
  double acc = 0.0;
  if (tid < 128) {
    up_lds(0, t[(85 + blk)*7], gi, g8, asp, sm_bT, sBeta, sNum, true);   // root numbeta
    acc += down_lds(0, t[(85 + blk)*7], sEps[gi], gi, g8, asp, aal, lsp,
                    log_bT, sBeta, sNum);
  }
  __syncthreads();
  {                                         // level 5 (locals 1..4)
    int v = 1 + w;
    acc += down_lds(v, t[(341 + blk*4 + w)*7], sBeta[v*GC + gi], gi, g8,
                    asp, aal, lsp, log_bT, sBeta, sNum);
  }
  __syncthreads();
  #pragma unroll
  for (int it = 0; it < 4; ++it) {          // level 6 (locals 5..20)
    int k = it*4 + w, v = 5 + k;
    acc += down_lds(v, t[(1365 + blk*16 + k)*7], sBeta[v*GC + gi], gi, g8,
                    asp, aal, lsp, log_bT, sBeta, sNum);
  }
  __syncthreads();
  #pragma unroll
  for (int it = 0; it < 16; ++it) {         // leaves: b_lh + pi_lh
    int k = it*4 + w;
    float e = sBeta[(21 + k)*GC + gi];
    acc += (double)(e * (log_bT[t[(base_leaf + k)*7]*GC + gi] +
                         log_piT[(k & 3)*GC + gi]));
  }
  acc += __shfl_xor(acc, 1);
  acc += __shfl_xor(acc, 2);
  acc += __shfl_xor(acc, 4);
  if (i == 0) sd[tid >> 3] = acc;           // tid>>3 = w*16 + g (0..63)
  __syncthreads();
  if (tid < 16) {
    double s = sd[tid] + sd[16 + tid] + sd[32 + tid] + sd[48 + tid];
    atomicAdd(&out[tid], (float)s);
  }
}

extern "C" void kernel_launch(void* const* d_in, const int* in_sizes, int n_in,
                              void* d_out, int out_size, void* d_ws, size_t ws_size,
                              hipStream_t stream) {
  const int*   t  = (const int*)d_in[0];
  // d_in[1] = t_limits (tree shape is compile-time constant)
  const float* a  = (const float*)d_in[2];
  const float* b  = (const float*)d_in[3];
  const float* pi = (const float*)d_in[4];
  const float* sp = (const float*)d_in[5];
  float* out = (float*)d_out;

  char* w = (char*)d_ws;
  size_t off = 0;
  auto carve = [&](size_t bytes) -> void* {
    void* ptr = w + off;
    off += (bytes + 255) & ~(size_t)255;
    return ptr;
  };
  float* a_sp    = (float*)carve((size_t)16*8*8*4*4);
  float* log_a   = (float*)carve((size_t)16*8*8*4*4);
  float* sm_bT   = (float*)carve((size_t)256*GC*4);
  float* log_bT  = (float*)carve((size_t)256*GC*4);
  float* sm_piT  = (float*)carve((size_t)4*GC*4);
  float* log_piT = (float*)carve((size_t)4*GC*4);
  float* log_sp  = (float*)carve((size_t)16*4*4);
  float* betaG   = (float*)carve((size_t)341*GC*4);   // subtree-root betas

  setup_kernel<<<18, 256, 0, stream>>>(a, b, pi, sp, a_sp, log_a, sm_bT, log_bT,
                                       sm_piT, log_piT, log_sp, out);
  up_kernel<<<256, 512, 0, stream>>>(a_sp, sm_bT, sm_piT, t, betaG);
  downall_kernel<<<256, 512, 0, stream>>>(a_sp, log_a, log_sp, sm_bT, log_bT,
                                          sm_piT, log_piT, t, betaG, out);
}